// Round 4
// baseline (993.714 us; speedup 1.0000x reference)
//
#include <hip/hip_runtime.h>
#include <hip/hip_bf16.h>

// GCN: 4 layers. N=100000, E=1600000, F=H=128, C=40. fp32.
// R3 changes vs R2:
//  - gemm_f32_128 replaced by gemm_f32_full: full-K one-shot LDS staging
//    (64x64 block, 128 thr, 1 barrier, 66.5KB LDS -> 2 blocks/CU)
//  - agg/scatter reverted to R1 form (4B srcSorted + dinv gather; equal speed,
//    half the scatter write traffic vs int2 packing)

#define N_NODES 100000
#define N_EDGES 1600000

// ---------------- CSR build ----------------

__global__ void init_counts(int* counts, int* cursor, int n) {
    int i = blockIdx.x * blockDim.x + threadIdx.x;
    if (i < n) { counts[i] = 1; cursor[i] = 0; }
}

__global__ void count_edges(const int* __restrict__ dst, int* __restrict__ counts, int e) {
    int i = blockIdx.x * blockDim.x + threadIdx.x;
    if (i < e) atomicAdd(&counts[dst[i]], 1);
}

__global__ void compute_dinv(const int* __restrict__ counts, float* __restrict__ dinv, int n) {
    int i = blockIdx.x * blockDim.x + threadIdx.x;
    if (i < n) dinv[i] = 1.0f / sqrtf((float)counts[i]);
}

__global__ __launch_bounds__(256) void scan_phase1(const int* __restrict__ counts,
                                                   int* __restrict__ blockSums, int n) {
    __shared__ int red[256];
    int t = threadIdx.x;
    int base = blockIdx.x * 1024 + t * 4;
    int s = 0;
    if (base + 3 < n) {
        int4 v = *(const int4*)(counts + base);
        s = v.x + v.y + v.z + v.w - 4;
    } else {
        for (int j = 0; j < 4; j++) if (base + j < n) s += counts[base + j] - 1;
    }
    red[t] = s;
    __syncthreads();
    for (int off = 128; off > 0; off >>= 1) {
        if (t < off) red[t] += red[t + off];
        __syncthreads();
    }
    if (t == 0) blockSums[blockIdx.x] = red[0];
}

__global__ __launch_bounds__(1024) void scan_phase2(int* __restrict__ blockSums, int nb) {
    __shared__ int sh[1024];
    int t = threadIdx.x;
    sh[t] = (t < nb) ? blockSums[t] : 0;
    __syncthreads();
    for (int off = 1; off < 1024; off <<= 1) {
        int v = (t >= off) ? sh[t - off] : 0;
        __syncthreads();
        sh[t] += v;
        __syncthreads();
    }
    if (t < nb) blockSums[t] = (t == 0) ? 0 : sh[t - 1];
}

__global__ __launch_bounds__(256) void scan_phase3(const int* __restrict__ counts,
                                                   const int* __restrict__ blockSums,
                                                   int* __restrict__ offsets, int n, int total) {
    __shared__ int red[256];
    int t = threadIdx.x;
    int base = blockIdx.x * 1024 + t * 4;
    int c[4];
#pragma unroll
    for (int j = 0; j < 4; j++) c[j] = (base + j < n) ? counts[base + j] - 1 : 0;
    int s = c[0] + c[1] + c[2] + c[3];
    red[t] = s;
    __syncthreads();
    for (int off = 1; off < 256; off <<= 1) {
        int v = (t >= off) ? red[t - off] : 0;
        __syncthreads();
        red[t] += v;
        __syncthreads();
    }
    int prefix = blockSums[blockIdx.x] + ((t == 0) ? 0 : red[t - 1]);
#pragma unroll
    for (int j = 0; j < 4; j++) {
        if (base + j < n) offsets[base + j] = prefix;
        prefix += c[j];
    }
    if (blockIdx.x == 0 && t == 0) offsets[n] = total;
}

__global__ void scatter_edges(const int* __restrict__ src, const int* __restrict__ dst,
                              const int* __restrict__ offsets, int* __restrict__ cursor,
                              int* __restrict__ srcSorted, int e) {
    int i = blockIdx.x * blockDim.x + threadIdx.x;
    if (i < e) {
        int d = dst[i];
        int pos = offsets[d] + atomicAdd(&cursor[d], 1);
        srcSorted[pos] = src[i];
    }
}

// ---------------- GEMM: [M,128] @ [128,128] -> [M,128], full-K LDS ----------------
// grid (ceil(M/64), 2), 128 threads. As[64][132] natural + Bs[128][64].
// One barrier; 8x4 microtile; b128 LDS reads with 8-lane broadcast.

__global__ __launch_bounds__(128) void gemm_f32_full(const float* __restrict__ A,
                                                     const float* __restrict__ B,
                                                     float* __restrict__ C, int M) {
    __shared__ float As[64][132];   // [m][k], +4 pad
    __shared__ float Bs[128][64];   // [k][n]
    int t = threadIdx.x;
    int row0 = blockIdx.x * 64;
    int col0 = blockIdx.y * 64;

    // stage A: 64 rows x 128 k = 2048 float4, 16/thread, coalesced
#pragma unroll
    for (int it = 0; it < 16; ++it) {
        int g = t + it * 128;
        int row = g >> 5;           // 0..63
        int k4  = (g & 31) << 2;    // 0..124
        int gr = row0 + row; if (gr >= M) gr = M - 1;
        float4 v = *(const float4*)(A + (size_t)gr * 128 + k4);
        *(float4*)&As[row][k4] = v;
    }
    // stage B: 128 k x 64 n = 2048 float4, coalesced
#pragma unroll
    for (int it = 0; it < 16; ++it) {
        int g = t + it * 128;
        int k  = g >> 4;            // 0..127
        int c4 = (g & 15) << 2;     // 0..60
        float4 v = *(const float4*)(B + (size_t)k * 128 + col0 + c4);
        *(float4*)&Bs[k][c4] = v;
    }
    __syncthreads();

    int tr = (t & 7) * 8;    // row group
    int tc = (t >> 3) * 4;   // col group
    float acc[8][4];
#pragma unroll
    for (int i = 0; i < 8; i++)
#pragma unroll
        for (int j = 0; j < 4; j++) acc[i][j] = 0.0f;

    for (int k = 0; k < 128; k += 4) {
        float4 am[8];
#pragma unroll
        for (int i = 0; i < 8; i++) am[i] = *(const float4*)&As[tr + i][k];
#pragma unroll
        for (int j = 0; j < 4; j++) {
            float4 bv = *(const float4*)&Bs[k + j][tc];
#pragma unroll
            for (int i = 0; i < 8; i++) {
                float a = (j == 0) ? am[i].x : (j == 1) ? am[i].y : (j == 2) ? am[i].z : am[i].w;
                acc[i][0] += a * bv.x;
                acc[i][1] += a * bv.y;
                acc[i][2] += a * bv.z;
                acc[i][3] += a * bv.w;
            }
        }
    }

#pragma unroll
    for (int i = 0; i < 8; i++) {
        int gr = row0 + tr + i;
        if (gr < M) {
            float4 v = make_float4(acc[i][0], acc[i][1], acc[i][2], acc[i][3]);
            *(float4*)(C + (size_t)gr * 128 + col0 + tc) = v;
        }
    }
}

// ---------------- GEMM: [M,128] @ [128,40] -> [M,40] ----------------

__global__ __launch_bounds__(320) void gemm_f32_40(const float* __restrict__ A,
                                                   const float* __restrict__ B,
                                                   float* __restrict__ C, int M) {
    __shared__ float Ws[128][40];
    __shared__ float Xs[32][132];
    int t = threadIdx.x;
    int block_row = blockIdx.x * 32;

    for (int i = t; i < 128 * 40; i += 320) ((float*)Ws)[i] = B[i];
    for (int idx = t; idx < 1024; idx += 320) {
        int row = idx >> 5;
        int k4  = (idx & 31) << 2;
        int gr = block_row + row; if (gr >= M) gr = M - 1;
        float4 v = *(const float4*)(A + (size_t)gr * 128 + k4);
        *(float4*)&Xs[row][k4] = v;
    }
    __syncthreads();

    int r  = t / 10;
    int c0 = (t % 10) * 4;
    float4 acc = make_float4(0.f, 0.f, 0.f, 0.f);
    for (int k = 0; k < 128; k += 4) {
        float4 xv = *(const float4*)&Xs[r][k];
#pragma unroll
        for (int j = 0; j < 4; j++) {
            float xj = (j == 0) ? xv.x : (j == 1) ? xv.y : (j == 2) ? xv.z : xv.w;
            float4 wv = *(const float4*)&Ws[k + j][c0];
            acc.x += xj * wv.x; acc.y += xj * wv.y;
            acc.z += xj * wv.z; acc.w += xj * wv.w;
        }
    }
    int gr = block_row + r;
    if (gr < M) *(float4*)(C + (size_t)gr * 40 + c0) = acc;
}

// ---------------- CSR aggregation: one wave per node, 4-way unrolled (R1 form) ----

template <int NF, bool RELU>
__global__ __launch_bounds__(256) void agg_kernel(const float* __restrict__ h,
                                                  const float* __restrict__ dinv,
                                                  const int* __restrict__ offsets,
                                                  const int* __restrict__ srcSorted,
                                                  const float* __restrict__ bias,
                                                  float* __restrict__ out, int n) {
    int wave = threadIdx.x >> 6;
    int lane = threadIdx.x & 63;
    int node = blockIdx.x * 4 + wave;
    if (node >= n) return;

    int f = lane * 2;
    bool act = (f < NF);
    float di = dinv[node];

    float2 a0 = make_float2(0.f, 0.f), a1 = a0, a2 = a0, a3 = a0;
    if (act) {
        float2 hv = *(const float2*)(h + (size_t)node * NF + f);
        a0.x = di * hv.x; a0.y = di * hv.y;
    }

    int beg = offsets[node], end = offsets[node + 1];
    int idx = beg;
    for (; idx + 4 <= end; idx += 4) {
        int s0 = srcSorted[idx];
        int s1 = srcSorted[idx + 1];
        int s2 = srcSorted[idx + 2];
        int s3 = srcSorted[idx + 3];
        float w0 = dinv[s0], w1 = dinv[s1], w2 = dinv[s2], w3 = dinv[s3];
        if (act) {
            float2 h0 = *(const float2*)(h + (size_t)s0 * NF + f);
            float2 h1 = *(const float2*)(h + (size_t)s1 * NF + f);
            float2 h2 = *(const float2*)(h + (size_t)s2 * NF + f);
            float2 h3 = *(const float2*)(h + (size_t)s3 * NF + f);
            a0.x += w0 * h0.x; a0.y += w0 * h0.y;
            a1.x += w1 * h1.x; a1.y += w1 * h1.y;
            a2.x += w2 * h2.x; a2.y += w2 * h2.y;
            a3.x += w3 * h3.x; a3.y += w3 * h3.y;
        }
    }
    if (idx + 2 <= end) {
        int s0 = srcSorted[idx];
        int s1 = srcSorted[idx + 1];
        float w0 = dinv[s0], w1 = dinv[s1];
        if (act) {
            float2 h0 = *(const float2*)(h + (size_t)s0 * NF + f);
            float2 h1 = *(const float2*)(h + (size_t)s1 * NF + f);
            a0.x += w0 * h0.x; a0.y += w0 * h0.y;
            a1.x += w1 * h1.x; a1.y += w1 * h1.y;
        }
        idx += 2;
    }
    if (idx < end) {
        int s0 = srcSorted[idx];
        float w0 = dinv[s0];
        if (act) {
            float2 h0 = *(const float2*)(h + (size_t)s0 * NF + f);
            a2.x += w0 * h0.x; a2.y += w0 * h0.y;
        }
    }

    if (act) {
        float2 o;
        o.x = di * ((a0.x + a1.x) + (a2.x + a3.x)) + bias[f];
        o.y = di * ((a0.y + a1.y) + (a2.y + a3.y)) + bias[f + 1];
        if (RELU) { o.x = fmaxf(o.x, 0.f); o.y = fmaxf(o.y, 0.f); }
        *(float2*)(out + (size_t)node * NF + f) = o;
    }
}

// ---------------- orchestration ----------------

extern "C" void kernel_launch(void* const* d_in, const int* in_sizes, int n_in,
                              void* d_out, int out_size, void* d_ws, size_t ws_size,
                              hipStream_t stream) {
    const float* x  = (const float*)d_in[0];
    const int* edge = (const int*)d_in[1];
    const float* W1 = (const float*)d_in[2]; const float* b1 = (const float*)d_in[3];
    const float* W2 = (const float*)d_in[4]; const float* b2 = (const float*)d_in[5];
    const float* W3 = (const float*)d_in[6]; const float* b3 = (const float*)d_in[7];
    const float* W4 = (const float*)d_in[8]; const float* b4 = (const float*)d_in[9];

    const int N = in_sizes[0] / 128;      // 100000
    const int E = in_sizes[1] / 2;        // 1600000
    const int* src = edge;
    const int* dst = edge + E;

    float* out_final = (float*)d_out;                    // [N,40]
    float* x_latent  = (float*)d_out + (size_t)N * 40;   // [N,128]

    // workspace carve-up
    char* w = (char*)d_ws;
    int* counts    = (int*)w;  w += (size_t)N * 4;
    int* cursor    = (int*)w;  w += (size_t)N * 4;
    int* offsets   = (int*)w;  w += (size_t)(N + 4) * 4;
    float* dinv    = (float*)w; w += (size_t)N * 4;
    int* srcSorted = (int*)w;  w += (size_t)E * 4;
    int* blockSums = (int*)w;  w += (size_t)1024 * 4;
    w = (char*)(((uintptr_t)w + 255) & ~(uintptr_t)255);
    float* hA = (float*)w; w += (size_t)N * 128 * 4;
    float* hB = (float*)w; w += (size_t)N * 128 * 4;

    int gN = (N + 255) / 256;
    int gE = (E + 255) / 256;
    int nb = (N + 1023) / 1024;   // 98

    init_counts<<<gN, 256, 0, stream>>>(counts, cursor, N);
    count_edges<<<gE, 256, 0, stream>>>(dst, counts, E);
    compute_dinv<<<gN, 256, 0, stream>>>(counts, dinv, N);
    scan_phase1<<<nb, 256, 0, stream>>>(counts, blockSums, N);
    scan_phase2<<<1, 1024, 0, stream>>>(blockSums, nb);
    scan_phase3<<<nb, 256, 0, stream>>>(counts, blockSums, offsets, N, E);
    scatter_edges<<<gE, 256, 0, stream>>>(src, dst, offsets, cursor, srcSorted, E);

    dim3 gGemm((N + 63) / 64, 2);   // 1563 x 2
    int gAgg = (N + 3) / 4;         // 25000

    gemm_f32_full<<<gGemm, 128, 0, stream>>>(x, W1, hA, N);
    agg_kernel<128, true><<<gAgg, 256, 0, stream>>>(hA, dinv, offsets, srcSorted, b1, hB, N);
    gemm_f32_full<<<gGemm, 128, 0, stream>>>(hB, W2, hA, N);
    agg_kernel<128, true><<<gAgg, 256, 0, stream>>>(hA, dinv, offsets, srcSorted, b2, hB, N);
    gemm_f32_full<<<gGemm, 128, 0, stream>>>(hB, W3, hA, N);
    agg_kernel<128, true><<<gAgg, 256, 0, stream>>>(hA, dinv, offsets, srcSorted, b3, x_latent, N);
    gemm_f32_40<<<(N + 31) / 32, 320, 0, stream>>>(x_latent, W4, hA, N);
    agg_kernel<40, false><<<gAgg, 256, 0, stream>>>(hA, dinv, offsets, srcSorted, b4, out_final, N);
}

// Round 5
// 843.413 us; speedup vs baseline: 1.1782x; 1.1782x over previous
//
#include <hip/hip_runtime.h>
#include <hip/hip_bf16.h>

// GCN: 4 layers. N=100000, E=1600000, F=H=128, C=40. fp32.
// R4 changes vs R3:
//  - gemm_f32_full replaced by gemm_mfma: bf16-split (hi+lo) MFMA GEMM.
//    W pre-packed into 16x16x32 fragment layout (prep_wfrag), A read fp32 and
//    split in-registers. 4 products (AhWh+AhWl+AlWh+AlWl) -> ~1e-5 rel err.
//    No LDS; pure streaming + matrix cores. Expect ~25us/GEMM vs ~130.
//  - everything else unchanged from R3 (agg at 3.88 TB/s pattern ceiling).

#define N_NODES 100000
#define N_EDGES 1600000

typedef short s16x8 __attribute__((ext_vector_type(8)));
typedef float f32x4 __attribute__((ext_vector_type(4)));

// ---------------- CSR build ----------------

__global__ void init_counts(int* counts, int* cursor, int n) {
    int i = blockIdx.x * blockDim.x + threadIdx.x;
    if (i < n) { counts[i] = 1; cursor[i] = 0; }
}

__global__ void count_edges(const int* __restrict__ dst, int* __restrict__ counts, int e) {
    int i = blockIdx.x * blockDim.x + threadIdx.x;
    if (i < e) atomicAdd(&counts[dst[i]], 1);
}

__global__ void compute_dinv(const int* __restrict__ counts, float* __restrict__ dinv, int n) {
    int i = blockIdx.x * blockDim.x + threadIdx.x;
    if (i < n) dinv[i] = 1.0f / sqrtf((float)counts[i]);
}

__global__ __launch_bounds__(256) void scan_phase1(const int* __restrict__ counts,
                                                   int* __restrict__ blockSums, int n) {
    __shared__ int red[256];
    int t = threadIdx.x;
    int base = blockIdx.x * 1024 + t * 4;
    int s = 0;
    if (base + 3 < n) {
        int4 v = *(const int4*)(counts + base);
        s = v.x + v.y + v.z + v.w - 4;
    } else {
        for (int j = 0; j < 4; j++) if (base + j < n) s += counts[base + j] - 1;
    }
    red[t] = s;
    __syncthreads();
    for (int off = 128; off > 0; off >>= 1) {
        if (t < off) red[t] += red[t + off];
        __syncthreads();
    }
    if (t == 0) blockSums[blockIdx.x] = red[0];
}

__global__ __launch_bounds__(1024) void scan_phase2(int* __restrict__ blockSums, int nb) {
    __shared__ int sh[1024];
    int t = threadIdx.x;
    sh[t] = (t < nb) ? blockSums[t] : 0;
    __syncthreads();
    for (int off = 1; off < 1024; off <<= 1) {
        int v = (t >= off) ? sh[t - off] : 0;
        __syncthreads();
        sh[t] += v;
        __syncthreads();
    }
    if (t < nb) blockSums[t] = (t == 0) ? 0 : sh[t - 1];
}

__global__ __launch_bounds__(256) void scan_phase3(const int* __restrict__ counts,
                                                   const int* __restrict__ blockSums,
                                                   int* __restrict__ offsets, int n, int total) {
    __shared__ int red[256];
    int t = threadIdx.x;
    int base = blockIdx.x * 1024 + t * 4;
    int c[4];
#pragma unroll
    for (int j = 0; j < 4; j++) c[j] = (base + j < n) ? counts[base + j] - 1 : 0;
    int s = c[0] + c[1] + c[2] + c[3];
    red[t] = s;
    __syncthreads();
    for (int off = 1; off < 256; off <<= 1) {
        int v = (t >= off) ? red[t - off] : 0;
        __syncthreads();
        red[t] += v;
        __syncthreads();
    }
    int prefix = blockSums[blockIdx.x] + ((t == 0) ? 0 : red[t - 1]);
#pragma unroll
    for (int j = 0; j < 4; j++) {
        if (base + j < n) offsets[base + j] = prefix;
        prefix += c[j];
    }
    if (blockIdx.x == 0 && t == 0) offsets[n] = total;
}

__global__ void scatter_edges(const int* __restrict__ src, const int* __restrict__ dst,
                              const int* __restrict__ offsets, int* __restrict__ cursor,
                              int* __restrict__ srcSorted, int e) {
    int i = blockIdx.x * blockDim.x + threadIdx.x;
    if (i < e) {
        int d = dst[i];
        int pos = offsets[d] + atomicAdd(&cursor[d], 1);
        srcSorted[pos] = src[i];
    }
}

// ---------------- bf16 split helpers ----------------

__device__ inline void split_bf16(float f, unsigned short& h, unsigned short& l) {
    unsigned u = __float_as_uint(f);
    unsigned hr = (u + 0x7FFFu + ((u >> 16) & 1u)) >> 16;    // RNE to bf16
    h = (unsigned short)hr;
    float r = f - __uint_as_float(hr << 16);
    unsigned v = __float_as_uint(r);
    unsigned lr = (v + 0x7FFFu + ((v >> 16) & 1u)) >> 16;
    l = (unsigned short)lr;
}

// Pack W[128][128] into 16x16x32 B-fragment layout, split into hi/lo bf16.
// frag idx = (t<<11) + (c<<9) + (lane<<3) + j ;  k = 32c + 8*quad + j ; n = 16t + (lane&15)
__global__ __launch_bounds__(256) void prep_wfrag(const float* __restrict__ W,
                                                  short* __restrict__ wh,
                                                  short* __restrict__ wl) {
    int idx = blockIdx.x * 256 + threadIdx.x;   // 0..16383
    int j    = idx & 7;
    int lane = (idx >> 3) & 63;
    int c    = (idx >> 9) & 3;
    int t    = idx >> 11;
    int quad = lane >> 4;
    int n = (t << 4) | (lane & 15);
    int k = (c << 5) + (quad << 3) + j;
    unsigned short h, l;
    split_bf16(W[k * 128 + n], h, l);
    wh[idx] = (short)h;
    wl[idx] = (short)l;
}

// ---------------- GEMM: [M,128] @ [128,128], bf16-split MFMA ----------------
// grid (GX, 2), 256 thr (4 waves). Each wave: 16-row strip x 64 cols
// (col group = blockIdx.y), grid-strided over strips. W-frags held in VGPRs.

#define GEMM_GX 512

__global__ __launch_bounds__(256) void gemm_mfma(const float* __restrict__ A,
                                                 const short* __restrict__ wh,
                                                 const short* __restrict__ wl,
                                                 float* __restrict__ C, int M) {
    int wv   = threadIdx.x >> 6;
    int lane = threadIdx.x & 63;
    int quad = lane >> 4;
    int mm   = lane & 15;
    int tbase = blockIdx.y * 4;     // tile group: tiles tbase..tbase+3 (64 cols)

    // resident W fragments: [tt][c]
    s16x8 whf[4][4], wlf[4][4];
#pragma unroll
    for (int tt = 0; tt < 4; tt++)
#pragma unroll
        for (int c = 0; c < 4; c++) {
            int base = ((((tbase + tt) << 2) + c) << 6 | lane) << 3;
            whf[tt][c] = *(const s16x8*)(wh + base);
            wlf[tt][c] = *(const s16x8*)(wl + base);
        }

    int nStrips = M >> 4;   // 6250
    for (int s = blockIdx.x * 4 + wv; s < nStrips; s += GEMM_GX * 4) {
        const float* ap = A + (size_t)((s << 4) + mm) * 128 + (quad << 3);
        f32x4 acc[4];
#pragma unroll
        for (int tt = 0; tt < 4; tt++) acc[tt] = (f32x4){0.f, 0.f, 0.f, 0.f};

#pragma unroll
        for (int c = 0; c < 4; c++) {
            float av[8];
            *(float4*)&av[0] = *(const float4*)(ap + (c << 5));
            *(float4*)&av[4] = *(const float4*)(ap + (c << 5) + 4);
            union { s16x8 v; unsigned short u[8]; } ah, al;
#pragma unroll
            for (int j = 0; j < 8; j++) split_bf16(av[j], ah.u[j], al.u[j]);
#pragma unroll
            for (int tt = 0; tt < 4; tt++) {
                acc[tt] = __builtin_amdgcn_mfma_f32_16x16x32_bf16(ah.v, whf[tt][c], acc[tt], 0, 0, 0);
                acc[tt] = __builtin_amdgcn_mfma_f32_16x16x32_bf16(ah.v, wlf[tt][c], acc[tt], 0, 0, 0);
                acc[tt] = __builtin_amdgcn_mfma_f32_16x16x32_bf16(al.v, whf[tt][c], acc[tt], 0, 0, 0);
                acc[tt] = __builtin_amdgcn_mfma_f32_16x16x32_bf16(al.v, wlf[tt][c], acc[tt], 0, 0, 0);
            }
        }
        // C/D layout: col = lane&15, row = quad*4 + reg
        float* cp = C + (size_t)((s << 4) + (quad << 2)) * 128 + (tbase << 4) + mm;
#pragma unroll
        for (int tt = 0; tt < 4; tt++) {
#pragma unroll
            for (int r = 0; r < 4; r++) {
                cp[(size_t)r * 128 + (tt << 4)] = acc[tt][r];
            }
        }
    }
}

// ---------------- GEMM: [M,128] @ [128,40] -> [M,40] ----------------

__global__ __launch_bounds__(320) void gemm_f32_40(const float* __restrict__ A,
                                                   const float* __restrict__ B,
                                                   float* __restrict__ C, int M) {
    __shared__ float Ws[128][40];
    __shared__ float Xs[32][132];
    int t = threadIdx.x;
    int block_row = blockIdx.x * 32;

    for (int i = t; i < 128 * 40; i += 320) ((float*)Ws)[i] = B[i];
    for (int idx = t; idx < 1024; idx += 320) {
        int row = idx >> 5;
        int k4  = (idx & 31) << 2;
        int gr = block_row + row; if (gr >= M) gr = M - 1;
        float4 v = *(const float4*)(A + (size_t)gr * 128 + k4);
        *(float4*)&Xs[row][k4] = v;
    }
    __syncthreads();

    int r  = t / 10;
    int c0 = (t % 10) * 4;
    float4 acc = make_float4(0.f, 0.f, 0.f, 0.f);
    for (int k = 0; k < 128; k += 4) {
        float4 xv = *(const float4*)&Xs[r][k];
#pragma unroll
        for (int j = 0; j < 4; j++) {
            float xj = (j == 0) ? xv.x : (j == 1) ? xv.y : (j == 2) ? xv.z : xv.w;
            float4 wv = *(const float4*)&Ws[k + j][c0];
            acc.x += xj * wv.x; acc.y += xj * wv.y;
            acc.z += xj * wv.z; acc.w += xj * wv.w;
        }
    }
    int gr = block_row + r;
    if (gr < M) *(float4*)(C + (size_t)gr * 40 + c0) = acc;
}

// ---------------- CSR aggregation: one wave per node, 4-way unrolled ----------------

template <int NF, bool RELU>
__global__ __launch_bounds__(256) void agg_kernel(const float* __restrict__ h,
                                                  const float* __restrict__ dinv,
                                                  const int* __restrict__ offsets,
                                                  const int* __restrict__ srcSorted,
                                                  const float* __restrict__ bias,
                                                  float* __restrict__ out, int n) {
    int wave = threadIdx.x >> 6;
    int lane = threadIdx.x & 63;
    int node = blockIdx.x * 4 + wave;
    if (node >= n) return;

    int f = lane * 2;
    bool act = (f < NF);
    float di = dinv[node];

    float2 a0 = make_float2(0.f, 0.f), a1 = a0, a2 = a0, a3 = a0;
    if (act) {
        float2 hv = *(const float2*)(h + (size_t)node * NF + f);
        a0.x = di * hv.x; a0.y = di * hv.y;
    }

    int beg = offsets[node], end = offsets[node + 1];
    int idx = beg;
    for (; idx + 4 <= end; idx += 4) {
        int s0 = srcSorted[idx];
        int s1 = srcSorted[idx + 1];
        int s2 = srcSorted[idx + 2];
        int s3 = srcSorted[idx + 3];
        float w0 = dinv[s0], w1 = dinv[s1], w2 = dinv[s2], w3 = dinv[s3];
        if (act) {
            float2 h0 = *(const float2*)(h + (size_t)s0 * NF + f);
            float2 h1 = *(const float2*)(h + (size_t)s1 * NF + f);
            float2 h2 = *(const float2*)(h + (size_t)s2 * NF + f);
            float2 h3 = *(const float2*)(h + (size_t)s3 * NF + f);
            a0.x += w0 * h0.x; a0.y += w0 * h0.y;
            a1.x += w1 * h1.x; a1.y += w1 * h1.y;
            a2.x += w2 * h2.x; a2.y += w2 * h2.y;
            a3.x += w3 * h3.x; a3.y += w3 * h3.y;
        }
    }
    if (idx + 2 <= end) {
        int s0 = srcSorted[idx];
        int s1 = srcSorted[idx + 1];
        float w0 = dinv[s0], w1 = dinv[s1];
        if (act) {
            float2 h0 = *(const float2*)(h + (size_t)s0 * NF + f);
            float2 h1 = *(const float2*)(h + (size_t)s1 * NF + f);
            a0.x += w0 * h0.x; a0.y += w0 * h0.y;
            a1.x += w1 * h1.x; a1.y += w1 * h1.y;
        }
        idx += 2;
    }
    if (idx < end) {
        int s0 = srcSorted[idx];
        float w0 = dinv[s0];
        if (act) {
            float2 h0 = *(const float2*)(h + (size_t)s0 * NF + f);
            a2.x += w0 * h0.x; a2.y += w0 * h0.y;
        }
    }

    if (act) {
        float2 o;
        o.x = di * ((a0.x + a1.x) + (a2.x + a3.x)) + bias[f];
        o.y = di * ((a0.y + a1.y) + (a2.y + a3.y)) + bias[f + 1];
        if (RELU) { o.x = fmaxf(o.x, 0.f); o.y = fmaxf(o.y, 0.f); }
        *(float2*)(out + (size_t)node * NF + f) = o;
    }
}

// ---------------- orchestration ----------------

extern "C" void kernel_launch(void* const* d_in, const int* in_sizes, int n_in,
                              void* d_out, int out_size, void* d_ws, size_t ws_size,
                              hipStream_t stream) {
    const float* x  = (const float*)d_in[0];
    const int* edge = (const int*)d_in[1];
    const float* W1 = (const float*)d_in[2]; const float* b1 = (const float*)d_in[3];
    const float* W2 = (const float*)d_in[4]; const float* b2 = (const float*)d_in[5];
    const float* W3 = (const float*)d_in[6]; const float* b3 = (const float*)d_in[7];
    const float* W4 = (const float*)d_in[8]; const float* b4 = (const float*)d_in[9];

    const int N = in_sizes[0] / 128;      // 100000
    const int E = in_sizes[1] / 2;        // 1600000
    const int* src = edge;
    const int* dst = edge + E;

    float* out_final = (float*)d_out;                    // [N,40]
    float* x_latent  = (float*)d_out + (size_t)N * 40;   // [N,128]

    // workspace carve-up
    char* w = (char*)d_ws;
    int* counts    = (int*)w;  w += (size_t)N * 4;
    int* cursor    = (int*)w;  w += (size_t)N * 4;
    int* offsets   = (int*)w;  w += (size_t)(N + 4) * 4;
    float* dinv    = (float*)w; w += (size_t)N * 4;
    int* srcSorted = (int*)w;  w += (size_t)E * 4;
    int* blockSums = (int*)w;  w += (size_t)1024 * 4;
    short* wfrag   = (short*)w; w += (size_t)6 * 16384 * 2;   // 3 layers x {hi,lo}
    w = (char*)(((uintptr_t)w + 255) & ~(uintptr_t)255);
    float* hA = (float*)w; w += (size_t)N * 128 * 4;
    float* hB = (float*)w; w += (size_t)N * 128 * 4;

    short* wh1 = wfrag + 0 * 16384; short* wl1 = wfrag + 1 * 16384;
    short* wh2 = wfrag + 2 * 16384; short* wl2 = wfrag + 3 * 16384;
    short* wh3 = wfrag + 4 * 16384; short* wl3 = wfrag + 5 * 16384;

    int gN = (N + 255) / 256;
    int gE = (E + 255) / 256;
    int nb = (N + 1023) / 1024;   // 98

    init_counts<<<gN, 256, 0, stream>>>(counts, cursor, N);
    count_edges<<<gE, 256, 0, stream>>>(dst, counts, E);
    compute_dinv<<<gN, 256, 0, stream>>>(counts, dinv, N);
    scan_phase1<<<nb, 256, 0, stream>>>(counts, blockSums, N);
    scan_phase2<<<1, 1024, 0, stream>>>(blockSums, nb);
    scan_phase3<<<nb, 256, 0, stream>>>(counts, blockSums, offsets, N, E);
    scatter_edges<<<gE, 256, 0, stream>>>(src, dst, offsets, cursor, srcSorted, E);

    prep_wfrag<<<64, 256, 0, stream>>>(W1, wh1, wl1);
    prep_wfrag<<<64, 256, 0, stream>>>(W2, wh2, wl2);
    prep_wfrag<<<64, 256, 0, stream>>>(W3, wh3, wl3);

    dim3 gGemm(GEMM_GX, 2);
    int gAgg = (N + 3) / 4;   // 25000

    gemm_mfma<<<gGemm, 256, 0, stream>>>(x, wh1, wl1, hA, N);
    agg_kernel<128, true><<<gAgg, 256, 0, stream>>>(hA, dinv, offsets, srcSorted, b1, hB, N);
    gemm_mfma<<<gGemm, 256, 0, stream>>>(hB, wh2, wl2, hA, N);
    agg_kernel<128, true><<<gAgg, 256, 0, stream>>>(hA, dinv, offsets, srcSorted, b2, hB, N);
    gemm_mfma<<<gGemm, 256, 0, stream>>>(hB, wh3, wl3, hA, N);
    agg_kernel<128, true><<<gAgg, 256, 0, stream>>>(hA, dinv, offsets, srcSorted, b3, x_latent, N);
    gemm_f32_40<<<(N + 31) / 32, 320, 0, stream>>>(x_latent, W4, hA, N);
    agg_kernel<40, false><<<gAgg, 256, 0, stream>>>(hA, dinv, offsets, srcSorted, b4, out_final, N);
}

// Round 6
// 667.162 us; speedup vs baseline: 1.4895x; 1.2642x over previous
//
#include <hip/hip_runtime.h>
#include <hip/hip_bf16.h>
#include <hip/hip_fp16.h>

// GCN: 4 layers. N=100000, E=1600000, F=H=128, C=40. fp32 in/out.
// R5 changes vs R4:
//  - h (GEMM outputs) stored fp16; agg gathers fp16 rows (halves fabric bytes,
//    the measured agg ceiling), accumulates fp32, writes fp32.
//    agg FETCH 415MB -> ~208MB predicted; agg128 123us -> ~70us.
//  - agg outputs / x_latent / final out remain fp32 (error: fp16 round adds
//    ~4e-5 sigma/layer; predicted absmax ~5e-4 vs 1.2e-3 threshold).

#define N_NODES 100000
#define N_EDGES 1600000

typedef short s16x8 __attribute__((ext_vector_type(8)));
typedef float f32x4 __attribute__((ext_vector_type(4)));

// ---------------- CSR build ----------------

__global__ void init_counts(int* counts, int* cursor, int n) {
    int i = blockIdx.x * blockDim.x + threadIdx.x;
    if (i < n) { counts[i] = 1; cursor[i] = 0; }
}

__global__ void count_edges(const int* __restrict__ dst, int* __restrict__ counts, int e) {
    int i = blockIdx.x * blockDim.x + threadIdx.x;
    if (i < e) atomicAdd(&counts[dst[i]], 1);
}

__global__ void compute_dinv(const int* __restrict__ counts, float* __restrict__ dinv, int n) {
    int i = blockIdx.x * blockDim.x + threadIdx.x;
    if (i < n) dinv[i] = 1.0f / sqrtf((float)counts[i]);
}

__global__ __launch_bounds__(256) void scan_phase1(const int* __restrict__ counts,
                                                   int* __restrict__ blockSums, int n) {
    __shared__ int red[256];
    int t = threadIdx.x;
    int base = blockIdx.x * 1024 + t * 4;
    int s = 0;
    if (base + 3 < n) {
        int4 v = *(const int4*)(counts + base);
        s = v.x + v.y + v.z + v.w - 4;
    } else {
        for (int j = 0; j < 4; j++) if (base + j < n) s += counts[base + j] - 1;
    }
    red[t] = s;
    __syncthreads();
    for (int off = 128; off > 0; off >>= 1) {
        if (t < off) red[t] += red[t + off];
        __syncthreads();
    }
    if (t == 0) blockSums[blockIdx.x] = red[0];
}

__global__ __launch_bounds__(1024) void scan_phase2(int* __restrict__ blockSums, int nb) {
    __shared__ int sh[1024];
    int t = threadIdx.x;
    sh[t] = (t < nb) ? blockSums[t] : 0;
    __syncthreads();
    for (int off = 1; off < 1024; off <<= 1) {
        int v = (t >= off) ? sh[t - off] : 0;
        __syncthreads();
        sh[t] += v;
        __syncthreads();
    }
    if (t < nb) blockSums[t] = (t == 0) ? 0 : sh[t - 1];
}

__global__ __launch_bounds__(256) void scan_phase3(const int* __restrict__ counts,
                                                   const int* __restrict__ blockSums,
                                                   int* __restrict__ offsets, int n, int total) {
    __shared__ int red[256];
    int t = threadIdx.x;
    int base = blockIdx.x * 1024 + t * 4;
    int c[4];
#pragma unroll
    for (int j = 0; j < 4; j++) c[j] = (base + j < n) ? counts[base + j] - 1 : 0;
    int s = c[0] + c[1] + c[2] + c[3];
    red[t] = s;
    __syncthreads();
    for (int off = 1; off < 256; off <<= 1) {
        int v = (t >= off) ? red[t - off] : 0;
        __syncthreads();
        red[t] += v;
        __syncthreads();
    }
    int prefix = blockSums[blockIdx.x] + ((t == 0) ? 0 : red[t - 1]);
#pragma unroll
    for (int j = 0; j < 4; j++) {
        if (base + j < n) offsets[base + j] = prefix;
        prefix += c[j];
    }
    if (blockIdx.x == 0 && t == 0) offsets[n] = total;
}

__global__ void scatter_edges(const int* __restrict__ src, const int* __restrict__ dst,
                              const int* __restrict__ offsets, int* __restrict__ cursor,
                              int* __restrict__ srcSorted, int e) {
    int i = blockIdx.x * blockDim.x + threadIdx.x;
    if (i < e) {
        int d = dst[i];
        int pos = offsets[d] + atomicAdd(&cursor[d], 1);
        srcSorted[pos] = src[i];
    }
}

// ---------------- bf16 split helpers ----------------

__device__ inline void split_bf16(float f, unsigned short& h, unsigned short& l) {
    unsigned u = __float_as_uint(f);
    unsigned hr = (u + 0x7FFFu + ((u >> 16) & 1u)) >> 16;    // RNE to bf16
    h = (unsigned short)hr;
    float r = f - __uint_as_float(hr << 16);
    unsigned v = __float_as_uint(r);
    unsigned lr = (v + 0x7FFFu + ((v >> 16) & 1u)) >> 16;
    l = (unsigned short)lr;
}

// Pack W[128][128] into 16x16x32 B-fragment layout, split into hi/lo bf16.
__global__ __launch_bounds__(256) void prep_wfrag(const float* __restrict__ W,
                                                  short* __restrict__ wh,
                                                  short* __restrict__ wl) {
    int idx = blockIdx.x * 256 + threadIdx.x;   // 0..16383
    int j    = idx & 7;
    int lane = (idx >> 3) & 63;
    int c    = (idx >> 9) & 3;
    int t    = idx >> 11;
    int quad = lane >> 4;
    int n = (t << 4) | (lane & 15);
    int k = (c << 5) + (quad << 3) + j;
    unsigned short h, l;
    split_bf16(W[k * 128 + n], h, l);
    wh[idx] = (short)h;
    wl[idx] = (short)l;
}

// ---------------- GEMM: [M,128] @ [128,128], bf16-split MFMA, fp16 out ------

#define GEMM_GX 512

__global__ __launch_bounds__(256) void gemm_mfma(const float* __restrict__ A,
                                                 const short* __restrict__ wh,
                                                 const short* __restrict__ wl,
                                                 __half* __restrict__ C, int M) {
    int wv   = threadIdx.x >> 6;
    int lane = threadIdx.x & 63;
    int quad = lane >> 4;
    int mm   = lane & 15;
    int tbase = blockIdx.y * 4;

    s16x8 whf[4][4], wlf[4][4];
#pragma unroll
    for (int tt = 0; tt < 4; tt++)
#pragma unroll
        for (int c = 0; c < 4; c++) {
            int base = ((((tbase + tt) << 2) + c) << 6 | lane) << 3;
            whf[tt][c] = *(const s16x8*)(wh + base);
            wlf[tt][c] = *(const s16x8*)(wl + base);
        }

    int nStrips = M >> 4;
    for (int s = blockIdx.x * 4 + wv; s < nStrips; s += GEMM_GX * 4) {
        const float* ap = A + (size_t)((s << 4) + mm) * 128 + (quad << 3);
        f32x4 acc[4];
#pragma unroll
        for (int tt = 0; tt < 4; tt++) acc[tt] = (f32x4){0.f, 0.f, 0.f, 0.f};

#pragma unroll
        for (int c = 0; c < 4; c++) {
            float av[8];
            *(float4*)&av[0] = *(const float4*)(ap + (c << 5));
            *(float4*)&av[4] = *(const float4*)(ap + (c << 5) + 4);
            union { s16x8 v; unsigned short u[8]; } ah, al;
#pragma unroll
            for (int j = 0; j < 8; j++) split_bf16(av[j], ah.u[j], al.u[j]);
#pragma unroll
            for (int tt = 0; tt < 4; tt++) {
                acc[tt] = __builtin_amdgcn_mfma_f32_16x16x32_bf16(ah.v, whf[tt][c], acc[tt], 0, 0, 0);
                acc[tt] = __builtin_amdgcn_mfma_f32_16x16x32_bf16(ah.v, wlf[tt][c], acc[tt], 0, 0, 0);
                acc[tt] = __builtin_amdgcn_mfma_f32_16x16x32_bf16(al.v, whf[tt][c], acc[tt], 0, 0, 0);
                acc[tt] = __builtin_amdgcn_mfma_f32_16x16x32_bf16(al.v, wlf[tt][c], acc[tt], 0, 0, 0);
            }
        }
        // C/D layout: col = lane&15, row = quad*4 + reg
        __half* cp = C + (size_t)((s << 4) + (quad << 2)) * 128 + (tbase << 4) + mm;
#pragma unroll
        for (int tt = 0; tt < 4; tt++) {
#pragma unroll
            for (int r = 0; r < 4; r++) {
                cp[(size_t)r * 128 + (tt << 4)] = __float2half(acc[tt][r]);
            }
        }
    }
}

// ---------------- GEMM: [M,128] @ [128,40] -> fp16 [M,40] ----------------

__global__ __launch_bounds__(320) void gemm_f32_40(const float* __restrict__ A,
                                                   const float* __restrict__ B,
                                                   __half* __restrict__ C, int M) {
    __shared__ float Ws[128][40];
    __shared__ float Xs[32][132];
    int t = threadIdx.x;
    int block_row = blockIdx.x * 32;

    for (int i = t; i < 128 * 40; i += 320) ((float*)Ws)[i] = B[i];
    for (int idx = t; idx < 1024; idx += 320) {
        int row = idx >> 5;
        int k4  = (idx & 31) << 2;
        int gr = block_row + row; if (gr >= M) gr = M - 1;
        float4 v = *(const float4*)(A + (size_t)gr * 128 + k4);
        *(float4*)&Xs[row][k4] = v;
    }
    __syncthreads();

    int r  = t / 10;
    int c0 = (t % 10) * 4;
    float4 acc = make_float4(0.f, 0.f, 0.f, 0.f);
    for (int k = 0; k < 128; k += 4) {
        float4 xv = *(const float4*)&Xs[r][k];
#pragma unroll
        for (int j = 0; j < 4; j++) {
            float xj = (j == 0) ? xv.x : (j == 1) ? xv.y : (j == 2) ? xv.z : xv.w;
            float4 wv = *(const float4*)&Ws[k + j][c0];
            acc.x += xj * wv.x; acc.y += xj * wv.y;
            acc.z += xj * wv.z; acc.w += xj * wv.w;
        }
    }
    int gr = block_row + r;
    if (gr < M) {
        __half2* p = (__half2*)(C + (size_t)gr * 40 + c0);
        p[0] = __floats2half2_rn(acc.x, acc.y);
        p[1] = __floats2half2_rn(acc.z, acc.w);
    }
}

// ---------------- CSR aggregation: fp16 gather, fp32 accumulate ----------------
// out[i] = relu?( dinv[i] * (dinv[i]*h[i] + sum_s w_s*h[s]) + b )

template <int NF, bool RELU>
__global__ __launch_bounds__(256) void agg_kernel(const __half* __restrict__ h,
                                                  const float* __restrict__ dinv,
                                                  const int* __restrict__ offsets,
                                                  const int* __restrict__ srcSorted,
                                                  const float* __restrict__ bias,
                                                  float* __restrict__ out, int n) {
    int wave = threadIdx.x >> 6;
    int lane = threadIdx.x & 63;
    int node = blockIdx.x * 4 + wave;
    if (node >= n) return;

    int f = lane * 2;
    bool act = (f < NF);
    float di = dinv[node];

    float2 a0 = make_float2(0.f, 0.f), a1 = a0, a2 = a0, a3 = a0;
    if (act) {
        float2 hv = __half22float2(*(const __half2*)(h + (size_t)node * NF + f));
        a0.x = di * hv.x; a0.y = di * hv.y;
    }

    int beg = offsets[node], end = offsets[node + 1];
    int idx = beg;
    for (; idx + 4 <= end; idx += 4) {
        int s0 = srcSorted[idx];
        int s1 = srcSorted[idx + 1];
        int s2 = srcSorted[idx + 2];
        int s3 = srcSorted[idx + 3];
        float w0 = dinv[s0], w1 = dinv[s1], w2 = dinv[s2], w3 = dinv[s3];
        if (act) {
            float2 h0 = __half22float2(*(const __half2*)(h + (size_t)s0 * NF + f));
            float2 h1 = __half22float2(*(const __half2*)(h + (size_t)s1 * NF + f));
            float2 h2 = __half22float2(*(const __half2*)(h + (size_t)s2 * NF + f));
            float2 h3 = __half22float2(*(const __half2*)(h + (size_t)s3 * NF + f));
            a0.x += w0 * h0.x; a0.y += w0 * h0.y;
            a1.x += w1 * h1.x; a1.y += w1 * h1.y;
            a2.x += w2 * h2.x; a2.y += w2 * h2.y;
            a3.x += w3 * h3.x; a3.y += w3 * h3.y;
        }
    }
    if (idx + 2 <= end) {
        int s0 = srcSorted[idx];
        int s1 = srcSorted[idx + 1];
        float w0 = dinv[s0], w1 = dinv[s1];
        if (act) {
            float2 h0 = __half22float2(*(const __half2*)(h + (size_t)s0 * NF + f));
            float2 h1 = __half22float2(*(const __half2*)(h + (size_t)s1 * NF + f));
            a0.x += w0 * h0.x; a0.y += w0 * h0.y;
            a1.x += w1 * h1.x; a1.y += w1 * h1.y;
        }
        idx += 2;
    }
    if (idx < end) {
        int s0 = srcSorted[idx];
        float w0 = dinv[s0];
        if (act) {
            float2 h0 = __half22float2(*(const __half2*)(h + (size_t)s0 * NF + f));
            a2.x += w0 * h0.x; a2.y += w0 * h0.y;
        }
    }

    if (act) {
        float2 o;
        o.x = di * ((a0.x + a1.x) + (a2.x + a3.x)) + bias[f];
        o.y = di * ((a0.y + a1.y) + (a2.y + a3.y)) + bias[f + 1];
        if (RELU) { o.x = fmaxf(o.x, 0.f); o.y = fmaxf(o.y, 0.f); }
        *(float2*)(out + (size_t)node * NF + f) = o;
    }
}

// ---------------- orchestration ----------------

extern "C" void kernel_launch(void* const* d_in, const int* in_sizes, int n_in,
                              void* d_out, int out_size, void* d_ws, size_t ws_size,
                              hipStream_t stream) {
    const float* x  = (const float*)d_in[0];
    const int* edge = (const int*)d_in[1];
    const float* W1 = (const float*)d_in[2]; const float* b1 = (const float*)d_in[3];
    const float* W2 = (const float*)d_in[4]; const float* b2 = (const float*)d_in[5];
    const float* W3 = (const float*)d_in[6]; const float* b3 = (const float*)d_in[7];
    const float* W4 = (const float*)d_in[8]; const float* b4 = (const float*)d_in[9];

    const int N = in_sizes[0] / 128;      // 100000
    const int E = in_sizes[1] / 2;        // 1600000
    const int* src = edge;
    const int* dst = edge + E;

    float* out_final = (float*)d_out;                    // [N,40]
    float* x_latent  = (float*)d_out + (size_t)N * 40;   // [N,128]

    // workspace carve-up
    char* w = (char*)d_ws;
    int* counts    = (int*)w;  w += (size_t)N * 4;
    int* cursor    = (int*)w;  w += (size_t)N * 4;
    int* offsets   = (int*)w;  w += (size_t)(N + 4) * 4;
    float* dinv    = (float*)w; w += (size_t)N * 4;
    int* srcSorted = (int*)w;  w += (size_t)E * 4;
    int* blockSums = (int*)w;  w += (size_t)1024 * 4;
    short* wfrag   = (short*)w; w += (size_t)6 * 16384 * 2;   // 3 layers x {hi,lo}
    w = (char*)(((uintptr_t)w + 255) & ~(uintptr_t)255);
    __half* hA = (__half*)w; w += (size_t)N * 128 * 2;   // fp16 gemm out
    float*  hB = (float*)w;  w += (size_t)N * 128 * 4;   // fp32 agg out

    short* wh1 = wfrag + 0 * 16384; short* wl1 = wfrag + 1 * 16384;
    short* wh2 = wfrag + 2 * 16384; short* wl2 = wfrag + 3 * 16384;
    short* wh3 = wfrag + 4 * 16384; short* wl3 = wfrag + 5 * 16384;

    int gN = (N + 255) / 256;
    int gE = (E + 255) / 256;
    int nb = (N + 1023) / 1024;   // 98

    init_counts<<<gN, 256, 0, stream>>>(counts, cursor, N);
    count_edges<<<gE, 256, 0, stream>>>(dst, counts, E);
    compute_dinv<<<gN, 256, 0, stream>>>(counts, dinv, N);
    scan_phase1<<<nb, 256, 0, stream>>>(counts, blockSums, N);
    scan_phase2<<<1, 1024, 0, stream>>>(blockSums, nb);
    scan_phase3<<<nb, 256, 0, stream>>>(counts, blockSums, offsets, N, E);
    scatter_edges<<<gE, 256, 0, stream>>>(src, dst, offsets, cursor, srcSorted, E);

    prep_wfrag<<<64, 256, 0, stream>>>(W1, wh1, wl1);
    prep_wfrag<<<64, 256, 0, stream>>>(W2, wh2, wl2);
    prep_wfrag<<<64, 256, 0, stream>>>(W3, wh3, wl3);

    dim3 gGemm(GEMM_GX, 2);
    int gAgg = (N + 3) / 4;   // 25000

    gemm_mfma<<<gGemm, 256, 0, stream>>>(x, wh1, wl1, hA, N);
    agg_kernel<128, true><<<gAgg, 256, 0, stream>>>(hA, dinv, offsets, srcSorted, b1, hB, N);
    gemm_mfma<<<gGemm, 256, 0, stream>>>(hB, wh2, wl2, hA, N);
    agg_kernel<128, true><<<gAgg, 256, 0, stream>>>(hA, dinv, offsets, srcSorted, b2, hB, N);
    gemm_mfma<<<gGemm, 256, 0, stream>>>(hB, wh3, wl3, hA, N);
    agg_kernel<128, true><<<gAgg, 256, 0, stream>>>(hA, dinv, offsets, srcSorted, b3, x_latent, N);
    gemm_f32_40<<<(N + 31) / 32, 320, 0, stream>>>(x_latent, W4, hA, N);
    agg_kernel<40, false><<<gAgg, 256, 0, stream>>>(hA, dinv, offsets, srcSorted, b4, out_final, N);
}